// Round 5
// baseline (63.795 us; speedup 1.0000x reference)
//
#include <hip/hip_runtime.h>
#include <hip/hip_bf16.h>

#define MARGIN 1.0f
#define C_DIM 1024
#define POISON_U32 0xAAAAAAAAu  // harness re-poisons d_ws to 0xAA bytes

// ---------------------------------------------------------------------------
// Single fused kernel: one block per row (256 threads; thread t owns
// elements 4t..4t+3), plus a last-block finalize tail.
//
// Latency plan (R3/R4 post-mortems: 1 wave/SIMD occupancy -> the kernel's
// cost IS its serial memory-latency chain; overlap everything):
//   - issue score float4 load                      (independent)
//   - issue width-1 speculative mask word          (always in-bounds)
//   - issue 16 KB prefix-scan loads (mask dtype detection)
//   one sync, decode width; expected (uint8) case needs no further loads.
//
// Detection evidence (prefix = first 4096 words, <= buffer size at any
// width): bit0 byte==1 at offset>0 -> uint8; bit1 half==0x3F80/0x3C00 ->
// bf16/fp16; bit2 word==0x3F800000 -> fp32; none -> int32 {0,1}.
//
// Fusion via poison-ticket (replaces the finalize_reduce dispatch):
//   tid0: store partial[row], partial[B+row]; __threadfence (release);
//   old = atomicAdd(ticket, 1). Last block iff old - X == B-1 for
//   X in {0xAAAAAAAA (documented timed-launch poison), 0 (possible
//   correctness-call convention)}. The two old-value ranges
//   {X..X+127} are disjoint and cross-match-free -> no double-finalize
//   race under either convention. Last block: __threadfence (acquire),
//   reduce 2B partials, write out[0].
// ---------------------------------------------------------------------------
__global__ __launch_bounds__(256) void row_loss_fused(
    const float* __restrict__ scores, const void* __restrict__ mask,
    int mask_elems, float* __restrict__ partial,
    unsigned int* __restrict__ ticket, float* __restrict__ out) {
    __shared__ float ps[C_DIM];  // compacted positive scores (worst case C)
    __shared__ int npos_sh;
    __shared__ unsigned int ev_sh;
    __shared__ float wsum[4], wden[4];
    __shared__ int last_flag;

    const int row = blockIdx.x;
    const int B = gridDim.x;
    const int tid = threadIdx.x;

    // ---- issue ALL independent global loads up front ---------------------
    const float4 sc = ((const float4*)scores)[row * 256 + tid];
    const unsigned int mw1 =
        ((const unsigned int*)mask)[row * 256 + tid];  // width-1 speculation

    int nwords = mask_elems / 4;  // elements >= bytes/4: safe lower bound
    if (nwords > 4096) nwords = 4096;
    const int nvec = nwords / 4;  // uint4 count (<= 1024 -> <= 4 per thread)
    uint4 q[4];
    int nq = 0;
#pragma unroll 4
    for (int i = tid; i < nvec; i += 256) q[nq++] = ((const uint4*)mask)[i];

    if (tid == 0) { npos_sh = 0; ev_sh = 0u; }
    __syncthreads();

    // ---- dtype evidence from the prefix ----------------------------------
    {
        unsigned int ev = 0u;
        for (int k = 0; k < nq; ++k) {
            unsigned int xs[4] = {q[k].x, q[k].y, q[k].z, q[k].w};
#pragma unroll
            for (int c = 0; c < 4; ++c) {
                unsigned int x = xs[c];
                if (x == 0u) continue;
                if (x == 0x3F800000u) ev |= 4u;
                unsigned int h0 = x & 0xFFFFu, h1 = x >> 16;
                if (h0 == 0x3F80u || h1 == 0x3F80u || h0 == 0x3C00u ||
                    h1 == 0x3C00u)
                    ev |= 2u;
                if (((x >> 8) & 0xFFu) == 1u || ((x >> 16) & 0xFFu) == 1u ||
                    ((x >> 24) & 0xFFu) == 1u)
                    ev |= 1u;
            }
        }
        if (ev) atomicOr(&ev_sh, ev);
    }
    __syncthreads();
    const unsigned int f = ev_sh;

    // ---- per-thread positive flags for elements 4t..4t+3 -----------------
    bool fl[4];
    if (f & 1u) {  // uint8 (expected): use the speculative preload
        fl[0] = (mw1 & 0xFFu) != 0u;
        fl[1] = ((mw1 >> 8) & 0xFFu) != 0u;
        fl[2] = ((mw1 >> 16) & 0xFFu) != 0u;
        fl[3] = ((mw1 >> 24) & 0xFFu) != 0u;
    } else if (f & 2u) {  // 2-byte: in-bounds iff detection correct
        uint2 h = ((const uint2*)mask)[row * 256 + tid];
        fl[0] = (h.x & 0xFFFFu) != 0u;
        fl[1] = (h.x >> 16) != 0u;
        fl[2] = (h.y & 0xFFFFu) != 0u;
        fl[3] = (h.y >> 16) != 0u;
    } else {  // 4-byte (int32 {0,1} or fp32): in-bounds iff detection correct
        uint4 w = ((const uint4*)mask)[row * 256 + tid];
        fl[0] = w.x != 0u; fl[1] = w.y != 0u;
        fl[2] = w.z != 0u; fl[3] = w.w != 0u;
    }

    // ---- compact positive scores into LDS --------------------------------
    const float sv[4] = {sc.x, sc.y, sc.z, sc.w};
#pragma unroll
    for (int c = 0; c < 4; ++c) {
        if (fl[c]) {
            int k = atomicAdd(&npos_sh, 1);
            ps[k] = sv[c];
        }
    }
    __syncthreads();

    // ---- pairwise hinge over own negatives -------------------------------
    const int np = npos_sh;
    float local = 0.0f;
#pragma unroll
    for (int c = 0; c < 4; ++c) {
        if (!fl[c]) {
            const float sn = sv[c] + MARGIN;
            for (int j = 0; j < np; ++j) local += fmaxf(sn - ps[j], 0.0f);
        }
    }

    for (int off = 32; off > 0; off >>= 1) local += __shfl_down(local, off);
    if ((tid & 63) == 0) wsum[tid >> 6] = local;
    __syncthreads();

    // ---- publish partials + poison-ticket --------------------------------
    if (tid == 0) {
        partial[row] = wsum[0] + wsum[1] + wsum[2] + wsum[3];
        partial[B + row] = (float)np * (float)(C_DIM - np);
        __threadfence();  // release: partials visible before ticket bump
        const unsigned int old = atomicAdd(ticket, 1u);
        const unsigned int n1 = (unsigned int)(B - 1);
        last_flag = ((old - POISON_U32) == n1) || (old == n1);
    }
    __syncthreads();

    // ---- last block: reduce all partials, finalize -----------------------
    if (last_flag) {
        __threadfence();  // acquire: see all other blocks' partials
        float l = 0.0f, d = 0.0f;
        for (int i = tid; i < B; i += 256) {
            l += partial[i];
            d += partial[B + i];
        }
        for (int off = 32; off > 0; off >>= 1) {
            l += __shfl_down(l, off);
            d += __shfl_down(d, off);
        }
        if ((tid & 63) == 0) { wsum[tid >> 6] = l; wden[tid >> 6] = d; }
        __syncthreads();
        if (tid == 0) {
            const float L = wsum[0] + wsum[1] + wsum[2] + wsum[3];
            const float D = wden[0] + wden[1] + wden[2] + wden[3];
            out[0] = (D == 0.0f) ? 0.0f : L / D;
        }
    }
}

extern "C" void kernel_launch(void* const* d_in, const int* in_sizes, int n_in,
                              void* d_out, int out_size, void* d_ws,
                              size_t ws_size, hipStream_t stream) {
    const float* scores = (const float*)d_in[0];
    const void* mask = d_in[1];

    const int B = in_sizes[0] / C_DIM;       // 128 for the reference shape
    float* partial = (float*)d_ws;           // [0,B): loss, [B,2B): denom
    unsigned int* ticket = (unsigned int*)d_ws + 2 * B;

    row_loss_fused<<<B, 256, 0, stream>>>(scores, mask, in_sizes[1], partial,
                                          ticket, (float*)d_out);
}

// Round 6
// 61.071 us; speedup vs baseline: 1.0446x; 1.0446x over previous
//
#include <hip/hip_runtime.h>
#include <hip/hip_bf16.h>

#define MARGIN 1.0f
#define C_DIM 1024

// ---------------------------------------------------------------------------
// R6 = revert to the R4 two-dispatch structure (best measured: 61.6 us).
// R5's single-kernel poison-ticket fusion was correct but neutral-to-worse:
// the last-block finalize tail (release fence + cross-XCD ticket + cold
// partial reads) costs about one graph-replayed dispatch, with a more
// fragile correctness story. Keeping the simpler 2-dispatch form.
//
// Kernel 1: one block per row (256 threads; thread t owns elements 4t..4t+3).
// Latency plan (R3/R4: 1 wave/SIMD occupancy -> cost IS the serial memory-
// latency chain; overlap everything):
//   - issue score float4 load                      (independent)
//   - issue width-1 speculative mask word          (always in-bounds)
//   - issue 16 KB prefix-scan loads (mask dtype detection)
//   one sync, decode width; expected (uint8) case needs no further loads.
//
// Detection evidence (prefix = first 4096 words, <= buffer size at any
// width): bit0 byte==1 at offset>0 -> uint8; bit1 half==0x3F80/0x3C00 ->
// bf16/fp16; bit2 word==0x3F800000 -> fp32; none -> int32 {0,1}.
//
// Output (plain stores, no init needed):
//   partial[row]     = sum_{n in neg, p in pos} relu(s_n - s_p + margin)
//   partial[B + row] = n_pos * (C - n_pos)
// ---------------------------------------------------------------------------
__global__ __launch_bounds__(256) void row_loss_fused(
    const float* __restrict__ scores, const void* __restrict__ mask,
    int mask_elems, float* __restrict__ partial) {
    __shared__ float ps[C_DIM];  // compacted positive scores (worst case C)
    __shared__ int npos_sh;
    __shared__ unsigned int ev_sh;
    __shared__ float wsum[4];

    const int row = blockIdx.x;
    const int tid = threadIdx.x;

    // ---- issue ALL independent global loads up front ---------------------
    const float4 sc = ((const float4*)scores)[row * 256 + tid];
    const unsigned int mw1 =
        ((const unsigned int*)mask)[row * 256 + tid];  // width-1 speculation

    int nwords = mask_elems / 4;  // elements >= bytes/4: safe lower bound
    if (nwords > 4096) nwords = 4096;
    const int nvec = nwords / 4;  // uint4 count (<= 1024 -> <= 4 per thread)
    uint4 q[4];
    int nq = 0;
#pragma unroll 4
    for (int i = tid; i < nvec; i += 256) q[nq++] = ((const uint4*)mask)[i];

    if (tid == 0) { npos_sh = 0; ev_sh = 0u; }
    __syncthreads();

    // ---- dtype evidence from the prefix ----------------------------------
    {
        unsigned int ev = 0u;
        for (int k = 0; k < nq; ++k) {
            unsigned int xs[4] = {q[k].x, q[k].y, q[k].z, q[k].w};
#pragma unroll
            for (int c = 0; c < 4; ++c) {
                unsigned int x = xs[c];
                if (x == 0u) continue;
                if (x == 0x3F800000u) ev |= 4u;
                unsigned int h0 = x & 0xFFFFu, h1 = x >> 16;
                if (h0 == 0x3F80u || h1 == 0x3F80u || h0 == 0x3C00u ||
                    h1 == 0x3C00u)
                    ev |= 2u;
                if (((x >> 8) & 0xFFu) == 1u || ((x >> 16) & 0xFFu) == 1u ||
                    ((x >> 24) & 0xFFu) == 1u)
                    ev |= 1u;
            }
        }
        if (ev) atomicOr(&ev_sh, ev);
    }
    __syncthreads();
    const unsigned int f = ev_sh;

    // ---- per-thread positive flags for elements 4t..4t+3 -----------------
    bool fl[4];
    if (f & 1u) {  // uint8 (expected): use the speculative preload
        fl[0] = (mw1 & 0xFFu) != 0u;
        fl[1] = ((mw1 >> 8) & 0xFFu) != 0u;
        fl[2] = ((mw1 >> 16) & 0xFFu) != 0u;
        fl[3] = ((mw1 >> 24) & 0xFFu) != 0u;
    } else if (f & 2u) {  // 2-byte: in-bounds iff detection correct
        uint2 h = ((const uint2*)mask)[row * 256 + tid];
        fl[0] = (h.x & 0xFFFFu) != 0u;
        fl[1] = (h.x >> 16) != 0u;
        fl[2] = (h.y & 0xFFFFu) != 0u;
        fl[3] = (h.y >> 16) != 0u;
    } else {  // 4-byte (int32 {0,1} or fp32): in-bounds iff detection correct
        uint4 w = ((const uint4*)mask)[row * 256 + tid];
        fl[0] = w.x != 0u; fl[1] = w.y != 0u;
        fl[2] = w.z != 0u; fl[3] = w.w != 0u;
    }

    // ---- compact positive scores into LDS --------------------------------
    const float sv[4] = {sc.x, sc.y, sc.z, sc.w};
#pragma unroll
    for (int c = 0; c < 4; ++c) {
        if (fl[c]) {
            int k = atomicAdd(&npos_sh, 1);
            ps[k] = sv[c];
        }
    }
    __syncthreads();

    // ---- pairwise hinge over own negatives -------------------------------
    const int np = npos_sh;
    float local = 0.0f;
#pragma unroll
    for (int c = 0; c < 4; ++c) {
        if (!fl[c]) {
            const float sn = sv[c] + MARGIN;
            for (int j = 0; j < np; ++j) local += fmaxf(sn - ps[j], 0.0f);
        }
    }

    for (int off = 32; off > 0; off >>= 1) local += __shfl_down(local, off);
    if ((tid & 63) == 0) wsum[tid >> 6] = local;
    __syncthreads();
    if (tid == 0) {
        partial[row] = wsum[0] + wsum[1] + wsum[2] + wsum[3];
        partial[gridDim.x + row] = (float)np * (float)(C_DIM - np);
    }
}

// ---------------------------------------------------------------------------
// Kernel 2: reduce per-row partials and finalize the scalar.
// ---------------------------------------------------------------------------
__global__ __launch_bounds__(256) void finalize_reduce(
    const float* __restrict__ partial, int B, float* __restrict__ out) {
    __shared__ float wl[4], wd[4];
    float l = 0.0f, d = 0.0f;
    for (int i = threadIdx.x; i < B; i += 256) {
        l += partial[i];
        d += partial[B + i];
    }
    for (int off = 32; off > 0; off >>= 1) {
        l += __shfl_down(l, off);
        d += __shfl_down(d, off);
    }
    const int lane = threadIdx.x & 63, wave = threadIdx.x >> 6;
    if (lane == 0) { wl[wave] = l; wd[wave] = d; }
    __syncthreads();
    if (threadIdx.x == 0) {
        const float L = wl[0] + wl[1] + wl[2] + wl[3];
        const float D = wd[0] + wd[1] + wd[2] + wd[3];
        out[0] = (D == 0.0f) ? 0.0f : L / D;
    }
}

extern "C" void kernel_launch(void* const* d_in, const int* in_sizes, int n_in,
                              void* d_out, int out_size, void* d_ws,
                              size_t ws_size, hipStream_t stream) {
    const float* scores = (const float*)d_in[0];
    const void* mask = d_in[1];

    const int B = in_sizes[0] / C_DIM;  // 128 for the reference shape
    float* partial = (float*)d_ws;      // [0,B): loss, [B,2B): denom

    row_loss_fused<<<B, 256, 0, stream>>>(scores, mask, in_sizes[1], partial);
    finalize_reduce<<<1, 256, 0, stream>>>(partial, B, (float*)d_out);
}